// Round 7
// baseline (342.290 us; speedup 1.0000x reference)
//
#include <hip/hip_runtime.h>
#include <stdint.h>
#include <stddef.h>

// ISNNet: x[:,0]=x0; x[:,t] = x[:,t-1] @ eW.T + I[:,t-1] @ W_inv_eW.T
// B=64, T=2048, D=256.  3-term compensated bf16 MFMA throughout.
// Round 7: k_u -> 16-wave WGs (16 cols/wave, 2x TLP); mm-power chain fused
// into one k_power launch (device spin barrier, 16 co-resident WGs);
// s_setprio around scan MFMA.

#define BATCH 64
#define TLEN 2048
#define DDIM 256
#define CHUNK 32
#define NCHUNK 64

typedef __attribute__((ext_vector_type(8))) short short8;
typedef __attribute__((ext_vector_type(4))) short short4_t;
typedef __attribute__((ext_vector_type(4))) float f32x4;

#define MFMA16(a, b, c) __builtin_amdgcn_mfma_f32_16x16x32_bf16((a), (b), (c), 0, 0, 0)
#define PIN8(x) asm volatile("" : "+v"(x))

__device__ __forceinline__ uint16_t f2bf(float f) {
  union { float f; uint32_t u; } v; v.f = f;
  return (uint16_t)((v.u + 0x7fffu + ((v.u >> 16) & 1u)) >> 16);  // RNE
}
__device__ __forceinline__ float bf2f(uint16_t h) {
  union { uint32_t u; float f; } v; v.u = ((uint32_t)h) << 16;
  return v.f;
}

__device__ __forceinline__ void split8(const float* fv, short8& hi, short8& lo) {
#pragma unroll
  for (int j = 0; j < 8; ++j) {
    uint16_t hb = f2bf(fv[j]);
    hi[j] = (short)hb;
    lo[j] = (short)f2bf(fv[j] - bf2f(hb));
  }
}

// rows 0..15 spread over 16 distinct 16B slots within 2 x 128B lines
__device__ __forceinline__ uint32_t swz(int row) {
  return ((uint32_t)((row & 7) << 4)) ^ ((uint32_t)(((row >> 3) & 1) << 7));
}

// raw barrier: waits LDS ops but NOT outstanding global loads
__device__ __forceinline__ void wg_barrier() {
  __builtin_amdgcn_sched_barrier(0);
  asm volatile("s_waitcnt lgkmcnt(0)" ::: "memory");
  __builtin_amdgcn_s_barrier();
  asm volatile("" ::: "memory");
  __builtin_amdgcn_sched_barrier(0);
}

// ---------------- workspace layout (bytes) ----------------
#define WS_A_HI   (0)
#define WS_A_LO   (128 * 1024)
#define WS_WB_HI  (256 * 1024)
#define WS_WB_LO  (384 * 1024)
#define WS_M1F    (512 * 1024)   // f32 [256][256]
#define WS_M1_HI  (768 * 1024)
#define WS_M1_LO  (896 * 1024)
#define WS_M2F    (1024 * 1024)
#define WS_M2_HI  (1280 * 1024)
#define WS_M2_LO  (1408 * 1024)
#define WS_M3F    (1536 * 1024)
#define WS_M3_HI  (1792 * 1024)
#define WS_M3_LO  (1920 * 1024)
#define WS_ATF    (2048 * 1024)  // f32 eW^T (A1 row-major), 256KB
#define WS_CNT    (2304 * 1024)  // spin-barrier counter
#define WS_S      (2560 * 1024)  // f32 [64][64][256] = 4MB
#define WS_Y      (6656 * 1024)  // f32 [64][64][256] = 4MB

// ---------------- k_split ----------------
__global__ void k_split(const float* __restrict__ eW, const float* __restrict__ Wi,
                        uint16_t* __restrict__ Ah, uint16_t* __restrict__ Al,
                        uint16_t* __restrict__ Wh, uint16_t* __restrict__ Wl,
                        float* __restrict__ AtF, unsigned int* __restrict__ cnt) {
  int idx = blockIdx.x * blockDim.x + threadIdx.x;
  if (idx == 0) *cnt = 0u;  // reset k_power's barrier counter every call
  if (idx < 65536) {
    float v = eW[idx];
    uint16_t h = f2bf(v);
    Ah[idx] = h;
    Al[idx] = f2bf(v - bf2f(h));
    AtF[(idx & 255) * 256 + (idx >> 8)] = v;  // AtF[k][n] = eW[n][k]
  } else if (idx < 131072) {
    int i = idx - 65536;
    float v = Wi[i];
    uint16_t h = f2bf(v);
    Wh[i] = h;
    Wl[i] = f2bf(v - bf2f(h));
  }
}

// ---------------- k_power: A^2..A^96 chain, ONE launch, 16 WGs ----------------
// Stage: OUT = Af @ B (256x256); each WG owns a 16-row slice (mf = blockIdx).
// Device-scope release/acquire spin barrier between stages (16 WGs co-resident).
__global__ __launch_bounds__(512) void k_power(
    const float* __restrict__ AtF, const uint16_t* __restrict__ Ah, const uint16_t* __restrict__ Al,
    float* __restrict__ M1f, uint16_t* __restrict__ M1h, uint16_t* __restrict__ M1l,
    float* __restrict__ M2f, uint16_t* __restrict__ M2h, uint16_t* __restrict__ M2l,
    float* __restrict__ M3f, uint16_t* __restrict__ M3h, uint16_t* __restrict__ M3l,
    unsigned int* __restrict__ cnt) {
  const int mf = blockIdx.x;  // 0..15
  const int tid = threadIdx.x;
  const int w = tid >> 6, l = tid & 63, l15 = l & 15, quad = l >> 4;
  const int ns = w * 32;

  auto mm = [&](const float* Af, const uint16_t* Bh, const uint16_t* Bl,
                float* Of, uint16_t* Oh, uint16_t* Ol) {
    f32x4 acc[2];
    acc[0] = {0.f, 0.f, 0.f, 0.f};
    acc[1] = {0.f, 0.f, 0.f, 0.f};
#pragma unroll
    for (int ks = 0; ks < 8; ++ks) {
      const float* ap = Af + (size_t)(mf * 16 + l15) * 256 + ks * 32 + quad * 8;
      f32x4 f0 = *reinterpret_cast<const f32x4*>(ap);
      f32x4 f1 = *reinterpret_cast<const f32x4*>(ap + 4);
      float fv[8] = {f0[0], f0[1], f0[2], f0[3], f1[0], f1[1], f1[2], f1[3]};
      short8 ah, al8;
      split8(fv, ah, al8);
#pragma unroll
      for (int nf = 0; nf < 2; ++nf) {
        const int off = (ns + nf * 16 + l15) * 256 + ks * 32 + quad * 8;
        short8 bhf = *reinterpret_cast<const short8*>(Bh + off);
        short8 blf = *reinterpret_cast<const short8*>(Bl + off);
        acc[nf] = MFMA16(ah, bhf, acc[nf]);
        acc[nf] = MFMA16(al8, bhf, acc[nf]);
        acc[nf] = MFMA16(ah, blf, acc[nf]);
      }
    }
#pragma unroll
    for (int nf = 0; nf < 2; ++nf)
#pragma unroll
      for (int r = 0; r < 4; ++r) {
        int row = mf * 16 + quad * 4 + r;
        int col = ns + nf * 16 + l15;
        float v = acc[nf][r];
        Of[(size_t)row * 256 + col] = v;
        uint16_t hb = f2bf(v);
        Oh[(size_t)col * 256 + row] = hb;
        Ol[(size_t)col * 256 + row] = f2bf(v - bf2f(hb));
      }
  };

  unsigned int target = 0;
  auto gbar = [&]() {
    __syncthreads();
    target += 16;
    if (tid == 0) {
      __hip_atomic_fetch_add(cnt, 1u, __ATOMIC_RELEASE, __HIP_MEMORY_SCOPE_AGENT);
      while (__hip_atomic_load(cnt, __ATOMIC_ACQUIRE, __HIP_MEMORY_SCOPE_AGENT) < target) {
      }
    }
    __syncthreads();
  };

  mm(AtF, Ah, Al, M2f, M2h, M2l);    gbar();  // A^2   (M2 as temp)
  mm(M2f, M2h, M2l, M3f, M3h, M3l);  gbar();  // A^4   (M3 as temp)
  mm(M3f, M3h, M3l, M2f, M2h, M2l);  gbar();  // A^8
  mm(M2f, M2h, M2l, M3f, M3h, M3l);  gbar();  // A^16
  mm(M3f, M3h, M3l, M1f, M1h, M1l);  gbar();  // A^32 -> M1
  mm(M1f, M1h, M1l, M2f, M2h, M2l);  gbar();  // A^64 -> M2
  mm(M2f, M1h, M1l, M3f, M3h, M3l);           // A^96 -> M3
}

// ---------------- k_u: u = I @ Wb, stored into d_out at time t+1 ----------------
// 16-wave WGs, 16 cols/wave (frags 64 VGPR). 256 WGs x 32 tiles; LDS dbuf.
__global__ __launch_bounds__(1024, 1) void k_u(const float* __restrict__ I,
                                               const uint16_t* __restrict__ Wh,
                                               const uint16_t* __restrict__ Wl,
                                               float* __restrict__ out) {
  const int tid = threadIdx.x;
  const int w = tid >> 6, l = tid & 63, l15 = l & 15, quad = l >> 4;
  const int ns = w * 16;  // 16 cols per wave
  __shared__ __align__(16) uint16_t sIh[2][4096];  // 16 x 256 bf16, XOR-swizzled
  __shared__ __align__(16) uint16_t sIl[2][4096];

  // Wb column-slice fragments (64 VGPR/wave, pinned)
  short8 bh[8], bl[8];
#pragma unroll
  for (int ks = 0; ks < 8; ++ks) {
    const int off = (ns + l15) * 256 + ks * 32 + quad * 8;
    bh[ks] = *reinterpret_cast<const short8*>(Wh + off);
    bl[ks] = *reinterpret_cast<const short8*>(Wl + off);
    PIN8(bh[ks]);
    PIN8(bl[ks]);
  }

  const int srow = tid >> 6;        // 0..15 (staging row = wave id)
  const int sc0 = (tid & 63) * 4;   // 0..252 (staging col base)
  const uint32_t wbyte = ((uint32_t)(srow * 512 + sc0 * 2)) ^ swz(srow);

  f32x4 ra, rb, rc, rd;
  auto loadI = [&](int tl, f32x4& dst) {
    const int b = tl >> 7, tt = tl & 127;
    dst = *reinterpret_cast<const f32x4*>(I + ((size_t)b * TLEN + tt * 16 + srow) * DDIM + sc0);
  };

  auto do_tile = [&](int tl, f32x4& cur, f32x4& pf, int q, bool pre) {
    if (pre) loadI(tl + 512, pf);    // prefetch tile tl+2 (stride 256)
    short4_t hi4, lo4;
#pragma unroll
    for (int j = 0; j < 4; ++j) {
      uint16_t hb = f2bf(cur[j]);
      hi4[j] = (short)hb;
      lo4[j] = (short)f2bf(cur[j] - bf2f(hb));
    }
    *reinterpret_cast<short4_t*>(reinterpret_cast<char*>(sIh[q]) + wbyte) = hi4;
    *reinterpret_cast<short4_t*>(reinterpret_cast<char*>(sIl[q]) + wbyte) = lo4;
    wg_barrier();                    // writes of buf q visible; buf q^1 free
    const int b = tl >> 7, tt = tl & 127;
    f32x4 acc = {0.f, 0.f, 0.f, 0.f};
    __builtin_amdgcn_s_setprio(1);
#pragma unroll
    for (int ks = 0; ks < 8; ++ks) {
      uint32_t rbyte = ((uint32_t)(l15 * 512 + ks * 64 + quad * 16)) ^ swz(l15);
      short8 ih = *reinterpret_cast<const short8*>((const char*)sIh[q] + rbyte);
      short8 il = *reinterpret_cast<const short8*>((const char*)sIl[q] + rbyte);
      acc = MFMA16(ih, bh[ks], acc);
      acc = MFMA16(il, bh[ks], acc);
      acc = MFMA16(ih, bl[ks], acc);
    }
    __builtin_amdgcn_s_setprio(0);
#pragma unroll
    for (int r = 0; r < 4; ++r) {
      int trow = tt * 16 + quad * 4 + r;
      if (trow <= TLEN - 2) {  // u_t lives at location t+1; t <= 2046
        out[((size_t)b * TLEN + trow + 1) * DDIM + ns + l15] = acc[r];
      }
    }
  };

  const int tl0 = blockIdx.x;  // 32 tiles: tl0 + k*256
  loadI(tl0, ra);
  loadI(tl0 + 256, rb);
#pragma unroll 1
  for (int it = 0; it < 32; it += 4) {
    do_tile(tl0 + (it + 0) * 256, ra, rc, 0, it + 2 < 32);
    do_tile(tl0 + (it + 1) * 256, rb, rd, 1, it + 3 < 32);
    do_tile(tl0 + (it + 2) * 256, rc, ra, 0, it + 4 < 32);
    do_tile(tl0 + (it + 3) * 256, rd, rb, 1, it + 5 < 32);
  }
}

// ---------------- k_scan: in-chunk recurrence (CHUNK=32), 16-wave WGs ----------------
__global__ __launch_bounds__(1024) void k_scan(const int pass,
                                               const uint16_t* __restrict__ Ah,
                                               const uint16_t* __restrict__ Al,
                                               float* __restrict__ xu,  // d_out: u in (shifted), x out
                                               const float* __restrict__ Y,
                                               float* __restrict__ S) {
  const int tid = threadIdx.x;
  const int w = tid >> 6, l = tid & 63, l15 = l & 15, quad = l >> 4;
  const int ns = w * 16;  // 16 cols per wave
  const int c = blockIdx.x >> 2;
  const int rg = blockIdx.x & 3;
  __shared__ __align__(16) uint16_t sh[2][4096];
  __shared__ __align__(16) uint16_t sl[2][4096];

  const int t0 = c * CHUNK;
  const int nsteps = (t0 + CHUNK <= TLEN - 1) ? CHUNK : (TLEN - 1 - t0);

  float u0[4], u1[4], u2[4], u3[4], fin[4];
#pragma unroll
  for (int j = 0; j < 4; ++j) { u0[j] = 0.f; u1[j] = 0.f; u2[j] = 0.f; u3[j] = 0.f; fin[j] = 0.f; }

  auto issue_u = [&](int i, float (&dst)[4]) {
    if (i > nsteps) return;
#pragma unroll
    for (int r = 0; r < 4; ++r) {
      int b = rg * 16 + quad * 4 + r;
      dst[r] = xu[((size_t)b * TLEN + t0 + i) * DDIM + ns + l15];
    }
  };
  issue_u(1, u0);
  issue_u(2, u1);
  issue_u(3, u2);
  issue_u(4, u3);

  // A fragments: per-wave 16-col slice (64 VGPR, pinned)
  short8 fAh[8], fAl[8];
#pragma unroll
  for (int ks = 0; ks < 8; ++ks) {
    const int off = (ns + l15) * 256 + ks * 32 + quad * 8;
    fAh[ks] = *reinterpret_cast<const short8*>(Ah + off);
    fAl[ks] = *reinterpret_cast<const short8*>(Al + off);
    PIN8(fAh[ks]);
    PIN8(fAl[ks]);
  }

  // init state (buf 0)
  for (int i = tid; i < 4096; i += 1024) {
    int row = i >> 8, k = i & 255;
    float v;
    if (pass == 1)
      v = 0.0f;
    else {
      v = Y[((size_t)c * 64 + rg * 16 + row) * DDIM + k];
      if (c == 0) xu[((size_t)(rg * 16 + row) * TLEN) * DDIM + k] = v;  // x[:,0,:] = x0
    }
    uint16_t hb = f2bf(v);
    uint16_t lb = f2bf(v - bf2f(hb));
    uint32_t byte = ((uint32_t)(row * 512 + k * 2)) ^ swz(row);
    *(uint16_t*)((char*)sh[0] + byte) = hb;
    *(uint16_t*)((char*)sl[0] + byte) = lb;
  }
  wg_barrier();  // no vmcnt drain: u prefetches stay in flight

  int p = 0;
  auto step = [&](int i, float (&ucur)[4]) {
    f32x4 acc = {0.f, 0.f, 0.f, 0.f};
    __builtin_amdgcn_s_setprio(1);
#pragma unroll
    for (int ks = 0; ks < 8; ++ks) {
      uint32_t byte = ((uint32_t)(l15 * 512 + ks * 64 + quad * 16)) ^ swz(l15);
      short8 xh = *reinterpret_cast<const short8*>((const char*)sh[p] + byte);
      short8 xl = *reinterpret_cast<const short8*>((const char*)sl[p] + byte);
      acc = MFMA16(xh, fAh[ks], acc);
      acc = MFMA16(xl, fAh[ks], acc);
      acc = MFMA16(xh, fAl[ks], acc);
    }
    __builtin_amdgcn_s_setprio(0);
#pragma unroll
    for (int r = 0; r < 4; ++r) fin[r] = acc[r] + ucur[r];
    issue_u(i + 4, ucur);  // refill this buffer for step i+4
    if (pass == 2) {
#pragma unroll
      for (int r = 0; r < 4; ++r) {
        int b = rg * 16 + quad * 4 + r;
        xu[((size_t)b * TLEN + t0 + i) * DDIM + ns + l15] = fin[r];
      }
    }
    if (i < nsteps) {
#pragma unroll
      for (int r = 0; r < 4; ++r) {
        int row = quad * 4 + r, col = ns + l15;
        float v = fin[r];
        uint16_t hb = f2bf(v);
        uint16_t lb = f2bf(v - bf2f(hb));
        uint32_t byte = ((uint32_t)(row * 512 + col * 2)) ^ swz(row);
        *(uint16_t*)((char*)sh[p ^ 1] + byte) = hb;
        *(uint16_t*)((char*)sl[p ^ 1] + byte) = lb;
      }
      wg_barrier();
      p ^= 1;
    }
  };

  int i = 1;
  for (; i + 3 <= nsteps; i += 4) {
    step(i, u0);
    step(i + 1, u1);
    step(i + 2, u2);
    step(i + 3, u3);
  }
  if (i <= nsteps) { step(i, u0); ++i; }
  if (i <= nsteps) { step(i, u1); ++i; }
  if (i <= nsteps) { step(i, u2); ++i; }

  if (pass == 1) {
#pragma unroll
    for (int r = 0; r < 4; ++r) {
      int row = quad * 4 + r, col = ns + l15;
      S[((size_t)c * 64 + rg * 16 + row) * DDIM + col] = fin[r];
    }
  }
}

// ---------------- k_bnd: boundary states, J=3 ----------------
// Y_c = T_c + T_{c-1}@M1 + T_{c-2}@M2 + T_{c-3}@M3; T_0=x0, T_k=S_{k-1}.
__global__ __launch_bounds__(512) void k_bnd(const float* __restrict__ x0,
                                             const float* __restrict__ S,
                                             const uint16_t* __restrict__ M1h, const uint16_t* __restrict__ M1l,
                                             const uint16_t* __restrict__ M2h, const uint16_t* __restrict__ M2l,
                                             const uint16_t* __restrict__ M3h, const uint16_t* __restrict__ M3l,
                                             float* __restrict__ Y) {
  const int c = blockIdx.x;
  const int tid = threadIdx.x;
  const int w = tid >> 6, l = tid & 63, l15 = l & 15, quad = l >> 4;
  const int ns = w * 32;
  f32x4 acc[4][2];
  const float* Tc = (c == 0) ? x0 : (S + (size_t)(c - 1) * 64 * 256);
#pragma unroll
  for (int mf = 0; mf < 4; ++mf)
#pragma unroll
    for (int nf = 0; nf < 2; ++nf)
#pragma unroll
      for (int r = 0; r < 4; ++r)
        acc[mf][nf][r] = Tc[(size_t)(mf * 16 + quad * 4 + r) * 256 + ns + nf * 16 + l15];

  for (int j = 1; j <= 3; ++j) {
    int k = c - j;
    if (k < 0) break;
    const float* Tp = (k == 0) ? x0 : (S + (size_t)(k - 1) * 64 * 256);
    const uint16_t* Bh = (j == 1) ? M1h : (j == 2) ? M2h : M3h;
    const uint16_t* Bl = (j == 1) ? M1l : (j == 2) ? M2l : M3l;
#pragma unroll
    for (int mf = 0; mf < 4; ++mf) {
#pragma unroll
      for (int ks = 0; ks < 8; ++ks) {
        const float* ap = Tp + (size_t)(mf * 16 + l15) * 256 + ks * 32 + quad * 8;
        f32x4 f0 = *reinterpret_cast<const f32x4*>(ap);
        f32x4 f1 = *reinterpret_cast<const f32x4*>(ap + 4);
        float fv[8] = {f0[0], f0[1], f0[2], f0[3], f1[0], f1[1], f1[2], f1[3]};
        short8 ah, al8;
        split8(fv, ah, al8);
#pragma unroll
        for (int nf = 0; nf < 2; ++nf) {
          const int off = (ns + nf * 16 + l15) * 256 + ks * 32 + quad * 8;
          short8 bhf = *reinterpret_cast<const short8*>(Bh + off);
          short8 blf = *reinterpret_cast<const short8*>(Bl + off);
          acc[mf][nf] = MFMA16(ah, bhf, acc[mf][nf]);
          acc[mf][nf] = MFMA16(al8, bhf, acc[mf][nf]);
          acc[mf][nf] = MFMA16(ah, blf, acc[mf][nf]);
        }
      }
    }
  }
#pragma unroll
  for (int mf = 0; mf < 4; ++mf)
#pragma unroll
    for (int nf = 0; nf < 2; ++nf)
#pragma unroll
      for (int r = 0; r < 4; ++r)
        Y[(size_t)c * 64 * 256 + (size_t)(mf * 16 + quad * 4 + r) * 256 + ns + nf * 16 + l15] =
            acc[mf][nf][r];
}

// ---------------- launch ----------------
extern "C" void kernel_launch(void* const* d_in, const int* in_sizes, int n_in,
                              void* d_out, int out_size, void* d_ws, size_t ws_size,
                              hipStream_t stream) {
  (void)in_sizes; (void)n_in; (void)out_size; (void)ws_size;
  const float* x0 = (const float*)d_in[0];
  const float* I  = (const float*)d_in[1];
  const float* eW = (const float*)d_in[2];
  const float* Wi = (const float*)d_in[3];
  float* out = (float*)d_out;
  char* ws = (char*)d_ws;

  uint16_t* Ah  = (uint16_t*)(ws + WS_A_HI);
  uint16_t* Al  = (uint16_t*)(ws + WS_A_LO);
  uint16_t* Wh  = (uint16_t*)(ws + WS_WB_HI);
  uint16_t* Wl  = (uint16_t*)(ws + WS_WB_LO);
  float*    M1f = (float*)(ws + WS_M1F);
  uint16_t* M1h = (uint16_t*)(ws + WS_M1_HI);
  uint16_t* M1l = (uint16_t*)(ws + WS_M1_LO);
  float*    M2f = (float*)(ws + WS_M2F);
  uint16_t* M2h = (uint16_t*)(ws + WS_M2_HI);
  uint16_t* M2l = (uint16_t*)(ws + WS_M2_LO);
  float*    M3f = (float*)(ws + WS_M3F);
  uint16_t* M3h = (uint16_t*)(ws + WS_M3_HI);
  uint16_t* M3l = (uint16_t*)(ws + WS_M3_LO);
  float*    AtF = (float*)(ws + WS_ATF);
  unsigned int* cnt = (unsigned int*)(ws + WS_CNT);
  float*    S   = (float*)(ws + WS_S);
  float*    Y   = (float*)(ws + WS_Y);

  k_split<<<512, 256, 0, stream>>>(eW, Wi, Ah, Al, Wh, Wl, AtF, cnt);
  k_power<<<16, 512, 0, stream>>>(AtF, Ah, Al, M1f, M1h, M1l, M2f, M2h, M2l,
                                  M3f, M3h, M3l, cnt);
  k_u<<<256, 1024, 0, stream>>>(I, Wh, Wl, out);
  k_scan<<<256, 1024, 0, stream>>>(1, Ah, Al, out, Y, S);
  k_bnd<<<64, 512, 0, stream>>>(x0, S, M1h, M1l, M2h, M2l, M3h, M3l, Y);
  k_scan<<<256, 1024, 0, stream>>>(2, Ah, Al, out, Y, S);
}